// Round 9
// baseline (1581.731 us; speedup 1.0000x reference)
//
#include <hip/hip_runtime.h>

// ForexLSTM: 2-layer LSTM (B=1024, T=512, D=14, H=128) + batchnorm-over-batch + MLP(128->32->1)
//
// Round 8: merged layers per wave at ONE j-group (the register-feasible merge).
// R5 merge @2jg: 384 weight regs -> spill. R7 split: regs fit but 96 b128/phase LDS
// weight re-reads + L0/L1 wave imbalance. R8: 512 thr / 8 waves, wave w owns j-group
// [16w,16w+16) of BOTH layers. Whh0+Wih1+Whh1 all register-resident (192 regs);
// Wih0 in LDS (4 b128/phase); h1f reads shared between L0's Whh0 and L1's Wih1 MFMAs.
// DS: 13 b128/wave/phase (h1f 4, h2f 4, xf 1, wih0 4). All waves identical: 52 MFMA.
// One barrier per phase, 513 phases: phase p = L0(t=p) + L1(t=p-1).
//   - All fragment layouts / activation math verbatim from validated R4/R7.
//   - bias0 folded via x_aug[15]=1; bias1 in 8 packed f16x2 regs.

#define B_ 1024
#define T_ 512
#define D_ 14
#define H_ 128
#define NB 4
#define NT 512

typedef _Float16 f16;
typedef _Float16 half4 __attribute__((ext_vector_type(4)));
typedef _Float16 half8 __attribute__((ext_vector_type(8)));
typedef _Float16 f16x2 __attribute__((ext_vector_type(2)));
typedef float floatx4 __attribute__((ext_vector_type(4)));

__device__ __forceinline__ float fexp(float x) {
    return __builtin_amdgcn_exp2f(x * 1.44269504088896f);
}
__device__ __forceinline__ float sigm(float x) {
    return __builtin_amdgcn_rcpf(1.0f + fexp(-x));
}
__device__ __forceinline__ float tanh_(float x) {
    return 1.0f - 2.0f * __builtin_amdgcn_rcpf(1.0f + fexp(2.0f * x));
}

__device__ __forceinline__ half8 ldfrag(const float* __restrict__ p) {
    half8 r;
#pragma unroll
    for (int j = 0; j < 8; ++j) r[j] = (f16)p[j];
    return r;
}

#define MFMA(a, b, c) __builtin_amdgcn_mfma_f32_16x16x32_f16((a), (b), (c), 0, 0, 0)

__global__ __launch_bounds__(NT, 2) void lstm_fused(
    const float* __restrict__ x,
    const float* __restrict__ Wih0, const float* __restrict__ Whh0,
    const float* __restrict__ bih0, const float* __restrict__ bhh0,
    const float* __restrict__ Wih1, const float* __restrict__ Whh1,
    const float* __restrict__ bih1, const float* __restrict__ bhh1,
    float* __restrict__ h2last)
{
    // LDS: 32 + 8 + 8 + 2 = 50 KB
    __shared__ __align__(16) f16 wih0lds[8][4][64][8];  // [wg][gate][lane][e] A-frags (aug)
    __shared__ __align__(16) f16 h1f[2][4][64][8];      // [buf][kt][lane][e] B-frag layout
    __shared__ __align__(16) f16 h2f[2][4][64][8];
    __shared__ __align__(16) f16 xf[2][64][8];          // x_aug (K=16: 14 x, 0, 1.0)

    const int tid = threadIdx.x;
    const int lane = tid & 63;
    const int wv = tid >> 6;          // wave 0..7 = j-group (both layers)
    const int n = lane & 15;          // batch column (valid < NB) / A-row index
    const int q = lane >> 4;          // quad -> D rows q*4+r
    const int b0 = blockIdx.x * NB;
    // h write-back target for j = wv*16 + q*4 + r
    const int ktw = wv >> 1;
    const int qw = (wv & 1) * 2 + (q >> 1);
    const int eb = (q & 1) * 4;

    // ---- register weights: A-frags A[m=lane&15][k=q*8+e], one j-group, 4 gates ----
    half8 aWhh0[4][4], aWih1[4][4], aWhh1[4][4];
    f16x2 b1p[4][2];
#pragma unroll
    for (int g = 0; g < 4; ++g) {
        const int gr = g * 128 + wv * 16 + n;
#pragma unroll
        for (int kt = 0; kt < 4; ++kt) {
            aWhh0[g][kt] = ldfrag(Whh0 + (size_t)gr * H_ + kt * 32 + q * 8);
            aWih1[g][kt] = ldfrag(Wih1 + (size_t)gr * H_ + kt * 32 + q * 8);
            aWhh1[g][kt] = ldfrag(Whh1 + (size_t)gr * H_ + kt * 32 + q * 8);
        }
        // Wih0 augmented A-frag -> LDS: k<14 = W, k==15 = bias0, k==14 = 0
        half8 w0;
#pragma unroll
        for (int e = 0; e < 8; ++e) {
            int k = q * 8 + e;
            if (k < D_)       w0[e] = (f16)Wih0[(size_t)gr * D_ + k];
            else if (k == 15) w0[e] = (f16)(bih0[gr] + bhh0[gr]);
            else              w0[e] = (f16)0.0f;
        }
        *(half8*)&wih0lds[wv][g][lane][0] = w0;
        const int gb = g * 128 + wv * 16 + q * 4;
        f16x2 p0, p1;
        p0[0] = (f16)(bih1[gb]     + bhh1[gb]);
        p0[1] = (f16)(bih1[gb + 1] + bhh1[gb + 1]);
        p1[0] = (f16)(bih1[gb + 2] + bhh1[gb + 2]);
        p1[1] = (f16)(bih1[gb + 3] + bhh1[gb + 3]);
        b1p[g][0] = p0;
        b1p[g][1] = p1;
    }

    // ---- zero state buffers: h1f,h2f = 4096 dwords total; xf = 512 dwords ----
    {
        unsigned int* z1 = (unsigned int*)h1f;
        unsigned int* z2 = (unsigned int*)h2f;
#pragma unroll
        for (int i = 0; i < 4; ++i) {
            z1[tid + i * 512] = 0u;
            z2[tid + i * 512] = 0u;
        }
        ((unsigned int*)xf)[tid] = 0u;
    }
    __syncthreads();

    // ---- x_aug constants (k==15 -> 1.0 in BOTH buffers) + stage x(0) into xf[0] ----
    if (tid < NB) {
        xf[0][tid + 16][7] = (f16)1.0f;
        xf[1][tid + 16][7] = (f16)1.0f;
    }
    if (tid < 64) {
        int nn = tid & 15, kq = tid >> 4;
        if (nn < NB && kq < 2) {
            half8 v;
#pragma unroll
            for (int e = 0; e < 8; ++e) {
                int k = kq * 8 + e;
                v[e] = (k < D_) ? (f16)x[(size_t)(b0 + nn) * T_ * D_ + k]
                                : (k == 15 ? (f16)1.0f : (f16)0.0f);
            }
            *(half8*)&xf[0][tid][0] = v;
        }
    }

    floatx4 c1 = {0.f, 0.f, 0.f, 0.f}, c2 = {0.f, 0.f, 0.f, 0.f};
    __syncthreads();

    // ======== 513 phases: phase p computes L0(t=p) and L1(t=p-1), all waves both ====
    for (int p = 0; p <= T_; ++p) {
        const int cur = p & 1, nxt = cur ^ 1;
        const bool doL0 = (p < T_);
        const bool doL1 = (p > 0);

        // x(p+1) prefetch into a register (threads 0..55, wave 0)
        float xp = 0.0f;
        if (tid < NB * D_ && (p + 1) < T_)
            xp = x[(size_t)(b0 + (tid & 3)) * T_ * D_ + (size_t)(p + 1) * D_ + (tid >> 2)];

        floatx4 C0[4], C1[4];
#pragma unroll
        for (int g = 0; g < 4; ++g) {
            C0[g] = floatx4{0.f, 0.f, 0.f, 0.f};
            C1[g] = floatx4{0.f, 0.f, 0.f, 0.f};
        }

        if (doL0) {
            half8 bx = *(const half8*)&xf[cur][lane][0];
#pragma unroll
            for (int g = 0; g < 4; ++g) {
                half8 aw = *(const half8*)&wih0lds[wv][g][lane][0];
                C0[g] = MFMA(aw, bx, C0[g]);
            }
        }
        // shared h1(p-1) reads: feed BOTH Whh0 (L0) and Wih1 (L1)
#pragma unroll
        for (int kt = 0; kt < 4; ++kt) {
            half8 bh = *(const half8*)&h1f[cur][kt][lane][0];
            if (doL0) {
#pragma unroll
                for (int g = 0; g < 4; ++g) C0[g] = MFMA(aWhh0[g][kt], bh, C0[g]);
            }
            if (doL1) {
#pragma unroll
                for (int g = 0; g < 4; ++g) C1[g] = MFMA(aWih1[g][kt], bh, C1[g]);
            }
        }
        if (doL1) {
#pragma unroll
            for (int kt = 0; kt < 4; ++kt) {
                half8 bh = *(const half8*)&h2f[cur][kt][lane][0];    // h2(p-2)
#pragma unroll
                for (int g = 0; g < 4; ++g) C1[g] = MFMA(aWhh1[g][kt], bh, C1[g]);
            }
        }

        // ---- L0 act + c1 update + h1(p) write ----
        if (doL0) {
            half4 hp;
#pragma unroll
            for (int r = 0; r < 4; ++r) {
                float i_ = sigm(C0[0][r]);
                float f_ = sigm(C0[1][r]);
                float g_ = tanh_(C0[2][r]);
                float o_ = sigm(C0[3][r]);
                c1[r] = f_ * c1[r] + i_ * g_;
                hp[r] = (f16)(o_ * tanh_(c1[r]));
            }
            if (n < NB) *(half4*)&h1f[nxt][ktw][n + 16 * qw][eb] = hp;
        }
        // ---- L1 act + c2 update + h2(p-1) write ----
        if (doL1) {
            half4 hp;
            floatx4 hv;
#pragma unroll
            for (int r = 0; r < 4; ++r) {
                float pi = C1[0][r] + (float)b1p[0][r >> 1][r & 1];
                float pf = C1[1][r] + (float)b1p[1][r >> 1][r & 1];
                float pg = C1[2][r] + (float)b1p[2][r >> 1][r & 1];
                float po = C1[3][r] + (float)b1p[3][r >> 1][r & 1];
                float i_ = sigm(pi), f_ = sigm(pf), g_ = tanh_(pg), o_ = sigm(po);
                c2[r] = f_ * c2[r] + i_ * g_;
                hv[r] = o_ * tanh_(c2[r]);
                hp[r] = (f16)hv[r];
            }
            if (n < NB) {
                *(half4*)&h2f[nxt][ktw][n + 16 * qw][eb] = hp;
                if (p == T_) {
#pragma unroll
                    for (int r = 0; r < 4; ++r)
                        h2last[(size_t)(b0 + n) * H_ + wv * 16 + q * 4 + r] = hv[r];
                }
            }
        }
        // restage x(p+1) (k slots 0..13; 14/15 constant from init)
        if (tid < NB * D_ && (p + 1) < T_) {
            int k = tid >> 2;
            xf[nxt][(tid & 3) + 16 * (k >> 3)][k & 7] = (f16)xp;
        }
        __syncthreads();
    }
}

// batch-norm statistics over the batch dim: 1 block, 1024 threads
__global__ void bn_stats(const float* __restrict__ h2last, float* __restrict__ stats)
{
    __shared__ float red[2][8][128];
    const int tid = threadIdx.x;
    const int j = tid & 127, bs = tid >> 7;
    float s = 0.0f, ss = 0.0f;
    for (int bb = 0; bb < 128; ++bb) {
        float v = h2last[(size_t)(bb * 8 + bs) * H_ + j];
        s += v;
        ss += v * v;
    }
    red[0][bs][j] = s;
    red[1][bs][j] = ss;
    __syncthreads();
    if (tid < 128) {
        float S = 0.0f, SS = 0.0f;
#pragma unroll
        for (int k = 0; k < 8; ++k) { S += red[0][k][tid]; SS += red[1][k][tid]; }
        float mu = S * (1.0f / 1024.0f);
        float var = SS * (1.0f / 1024.0f) - mu * mu;
        stats[tid] = mu;
        stats[128 + tid] = __builtin_amdgcn_rsqf(var + 1e-5f);
    }
}

// normalize + MLP head: 8 blocks x 128 threads, one batch element per thread
__global__ void bn_mlp(const float* __restrict__ h2last, const float* __restrict__ stats,
                       const float* __restrict__ gamma, const float* __restrict__ beta,
                       const float* __restrict__ W1, const float* __restrict__ b1,
                       const float* __restrict__ W2, const float* __restrict__ b2,
                       float* __restrict__ out)
{
    __shared__ float W1T[128][33];
    __shared__ float mus[128], isds[128], gs[128], bts[128], w2s[32];
    const int tid = threadIdx.x;
    const int b = blockIdx.x * 128 + tid;

    for (int i = tid; i < 4096; i += 128) {
        int k = i >> 7, j = i & 127;
        W1T[j][k] = W1[i];
    }
    mus[tid] = stats[tid];
    isds[tid] = stats[128 + tid];
    gs[tid] = gamma[tid];
    bts[tid] = beta[tid];
    if (tid < 32) w2s[tid] = W2[tid];
    __syncthreads();

    float z[32];
#pragma unroll
    for (int k = 0; k < 32; ++k) z[k] = b1[k];

    for (int j = 0; j < 128; ++j) {
        float nv = (h2last[(size_t)b * H_ + j] - mus[j]) * isds[j] * gs[j] + bts[j];
#pragma unroll
        for (int k = 0; k < 32; ++k) z[k] += W1T[j][k] * nv;
    }
    float o = b2[0];
#pragma unroll
    for (int k = 0; k < 32; ++k) o += w2s[k] * fmaxf(z[k], 0.0f);
    out[b] = o;
}

extern "C" void kernel_launch(void* const* d_in, const int* in_sizes, int n_in,
                              void* d_out, int out_size, void* d_ws, size_t ws_size,
                              hipStream_t stream)
{
    const float* x    = (const float*)d_in[0];
    const float* Wih0 = (const float*)d_in[1];
    const float* Whh0 = (const float*)d_in[2];
    const float* bih0 = (const float*)d_in[3];
    const float* bhh0 = (const float*)d_in[4];
    const float* Wih1 = (const float*)d_in[5];
    const float* Whh1 = (const float*)d_in[6];
    const float* bih1 = (const float*)d_in[7];
    const float* bhh1 = (const float*)d_in[8];
    const float* gamma = (const float*)d_in[9];
    const float* beta  = (const float*)d_in[10];
    const float* W1 = (const float*)d_in[11];
    const float* b1 = (const float*)d_in[12];
    const float* W2 = (const float*)d_in[13];
    const float* b2 = (const float*)d_in[14];

    float* h2last = (float*)d_ws;              // 1024*128 floats = 512 KB
    float* stats  = h2last + (size_t)B_ * H_;  // 256 floats
    float* out = (float*)d_out;

    hipLaunchKernelGGL(lstm_fused, dim3(B_ / NB), dim3(NT), 0, stream,
                       x, Wih0, Whh0, bih0, bhh0, Wih1, Whh1, bih1, bhh1, h2last);
    hipLaunchKernelGGL(bn_stats, dim3(1), dim3(1024), 0, stream, h2last, stats);
    hipLaunchKernelGGL(bn_mlp, dim3(8), dim3(128), 0, stream,
                       h2last, stats, gamma, beta, W1, b1, W2, b2, out);
}

// Round 10
// 1449.571 us; speedup vs baseline: 1.0912x; 1.0912x over previous
//
#include <hip/hip_runtime.h>

// ForexLSTM: 2-layer LSTM (B=1024, T=512, D=14, H=128) + batchnorm-over-batch + MLP(128->32->1)
//
// Round 9: R7 base (best, spill-free) + two targeted cuts:
//  (1) Whh1 kt1 promoted LDS->regs (group B): whh1lds reads 24->16 b128/wave/phase,
//      DS/CU/phase 148->116. Group-B live regs ~248 < 256 (R7 measured ~216 + 32).
//  (2) log2e folded into gate weights at load: i/f/o rows x1.4427, g rows x2.8854,
//      biases likewise. Activations become sigm=rcp(1+exp2(-y)), tanh=1-2*rcp(1+exp2(y))
//      -- saves ~6 VALU issue slots per state (16 lane-states/SIMD/phase).
// Everything else verbatim from R7: 512 thr / 8 waves; waves 0-3 layer-0 (2 j-groups
// each), waves 4-7 layer-1; one __syncthreads per phase, 513 phases; weights as MFMA
// A-frags, D[row=gate,col=batch]; h in B-frag LDS layout; bias0 folded via x_aug[15]=1.

#define B_ 1024
#define T_ 512
#define D_ 14
#define H_ 128
#define NB 4
#define NT 512

#define L2E 1.44269504088896f
#define L2E2 2.88539008177793f

typedef _Float16 f16;
typedef _Float16 half4 __attribute__((ext_vector_type(4)));
typedef _Float16 half8 __attribute__((ext_vector_type(8)));
typedef _Float16 f16x2 __attribute__((ext_vector_type(2)));
typedef float floatx4 __attribute__((ext_vector_type(4)));

// pre-scaled activations: y = x * L2E (sigm rows) or x * 2*L2E (tanh rows)
__device__ __forceinline__ float sigmP(float y) {
    return __builtin_amdgcn_rcpf(1.0f + __builtin_amdgcn_exp2f(-y));
}
__device__ __forceinline__ float tanhP(float y) {   // y = 2x*log2e
    return 1.0f - 2.0f * __builtin_amdgcn_rcpf(1.0f + __builtin_amdgcn_exp2f(y));
}
__device__ __forceinline__ float tanhC(float c) {   // c in true units
    return tanhP(c * L2E2);
}

__device__ __forceinline__ half8 ldfrag_s(const float* __restrict__ p, float s) {
    half8 r;
#pragma unroll
    for (int j = 0; j < 8; ++j) r[j] = (f16)(p[j] * s);
    return r;
}

#define MFMA(a, b, c) __builtin_amdgcn_mfma_f32_16x16x32_f16((a), (b), (c), 0, 0, 0)

__global__ __launch_bounds__(NT, 2) void lstm_fused(
    const float* __restrict__ x,
    const float* __restrict__ Wih0, const float* __restrict__ Whh0,
    const float* __restrict__ bih0, const float* __restrict__ bhh0,
    const float* __restrict__ Wih1, const float* __restrict__ Whh1,
    const float* __restrict__ bih1, const float* __restrict__ bhh1,
    float* __restrict__ h2last)
{
    // LDS: 64 + 8 + 8 + 2 = 82 KB
    __shared__ __align__(16) f16 whh1lds[8][4][2][64][8];  // [wg][gate][kt-2][lane][e]
    __shared__ __align__(16) f16 h1f[2][4][64][8];         // [buf][kt][lane][e] B-frag
    __shared__ __align__(16) f16 h2f[2][4][64][8];
    __shared__ __align__(16) f16 xf[2][64][8];             // x_aug (K=16: 14 x, 0, 1.0)

    const int tid = threadIdx.x;
    const int lane = tid & 63;
    const int wv = tid >> 6;          // wave 0..7
    const int n = lane & 15;          // batch column (valid < NB) / A-row index
    const int q = lane >> 4;          // quad -> D rows q*4+r
    const int b0 = blockIdx.x * NB;

    // ---- zero state buffers ----
    {
        unsigned int* z1 = (unsigned int*)h1f;
        unsigned int* z2 = (unsigned int*)h2f;
#pragma unroll
        for (int i = 0; i < 4; ++i) {
            z1[tid + i * 512] = 0u;
            z2[tid + i * 512] = 0u;
        }
        ((unsigned int*)xf)[tid] = 0u;
    }
    __syncthreads();

    // ---- x_aug constants (k==15 -> 1.0 in BOTH buffers) + stage x(0) into xf[0] ----
    if (tid < NB) {
        xf[0][tid + 16][7] = (f16)1.0f;
        xf[1][tid + 16][7] = (f16)1.0f;
    }
    if (tid < 64) {
        int nn = tid & 15, kq = tid >> 4;
        if (nn < NB && kq < 2) {
            half8 v;
#pragma unroll
            for (int e = 0; e < 8; ++e) {
                int k = kq * 8 + e;
                v[e] = (k < D_) ? (f16)x[(size_t)(b0 + nn) * T_ * D_ + k]
                                : (k == 15 ? (f16)1.0f : (f16)0.0f);
            }
            *(half8*)&xf[0][tid][0] = v;
        }
    }

    if (wv < 4) {
        // ================= GROUP A: layer-0, waves 0-3, j-groups {2wv, 2wv+1} ========
        half8 aWhh0[2][4][4], aWih0[2][4];
#pragma unroll
        for (int jj = 0; jj < 2; ++jj) {
            const int wg = 2 * wv + jj;
#pragma unroll
            for (int g = 0; g < 4; ++g) {
                const float gs = (g == 2) ? L2E2 : L2E;   // g-gate rows pre-scaled 2x
                const int gr = g * 128 + wg * 16 + n;
#pragma unroll
                for (int kt = 0; kt < 4; ++kt)
                    aWhh0[jj][g][kt] = ldfrag_s(Whh0 + (size_t)gr * H_ + kt * 32 + q * 8, gs);
                half8 w0;
#pragma unroll
                for (int e = 0; e < 8; ++e) {
                    int k = q * 8 + e;
                    if (k < D_)       w0[e] = (f16)(Wih0[(size_t)gr * D_ + k] * gs);
                    else if (k == 15) w0[e] = (f16)((bih0[gr] + bhh0[gr]) * gs);
                    else              w0[e] = (f16)0.0f;
                }
                aWih0[jj][g] = w0;
            }
        }
        floatx4 c1[2] = {{0.f, 0.f, 0.f, 0.f}, {0.f, 0.f, 0.f, 0.f}};
        __syncthreads();

        for (int p = 0; p <= T_; ++p) {
            const int cur = p & 1, nxt = cur ^ 1;
            if (p < T_) {
                float xp = 0.0f;
                if (tid < NB * D_ && (p + 1) < T_)
                    xp = x[(size_t)(b0 + (tid & 3)) * T_ * D_ + (size_t)(p + 1) * D_ + (tid >> 2)];

                floatx4 C0[2][4];
#pragma unroll
                for (int jj = 0; jj < 2; ++jj)
#pragma unroll
                    for (int g = 0; g < 4; ++g) C0[jj][g] = floatx4{0.f, 0.f, 0.f, 0.f};
                {
                    half8 bx = *(const half8*)&xf[cur][lane][0];
#pragma unroll
                    for (int jj = 0; jj < 2; ++jj)
#pragma unroll
                        for (int g = 0; g < 4; ++g) C0[jj][g] = MFMA(aWih0[jj][g], bx, C0[jj][g]);
                }
#pragma unroll
                for (int kt = 0; kt < 4; ++kt) {
                    half8 bh = *(const half8*)&h1f[cur][kt][lane][0];
#pragma unroll
                    for (int jj = 0; jj < 2; ++jj)
#pragma unroll
                        for (int g = 0; g < 4; ++g) C0[jj][g] = MFMA(aWhh0[jj][g][kt], bh, C0[jj][g]);
                }
#pragma unroll
                for (int jj = 0; jj < 2; ++jj) {
                    half4 hp;
#pragma unroll
                    for (int r = 0; r < 4; ++r) {
                        float i_ = sigmP(C0[jj][0][r]);
                        float f_ = sigmP(C0[jj][1][r]);
                        float g_ = tanhP(C0[jj][2][r]);
                        float o_ = sigmP(C0[jj][3][r]);
                        c1[jj][r] = f_ * c1[jj][r] + i_ * g_;
                        hp[r] = (f16)(o_ * tanhC(c1[jj][r]));
                    }
                    const int wg = 2 * wv + jj;
                    const int ktw = wg >> 1;
                    const int qw = (wg & 1) * 2 + (q >> 1);
                    const int eb = (q & 1) * 4;
                    if (n < NB) *(half4*)&h1f[nxt][ktw][n + 16 * qw][eb] = hp;
                }
                if (tid < NB * D_ && (p + 1) < T_) {
                    int k = tid >> 2;
                    xf[nxt][(tid & 3) + 16 * (k >> 3)][k & 7] = (f16)xp;
                }
            }
            __syncthreads();
        }
    } else {
        // ================= GROUP B: layer-1, waves 4-7, j-groups {2w, 2w+1} ==========
        const int w = wv - 4;
        half8 aWih1[2][4][4], aWhh1r[2][4][2];   // Whh1 kt0,kt1 in regs; kt2,3 in LDS
        f16x2 b1p[2][4][2];
#pragma unroll
        for (int jj = 0; jj < 2; ++jj) {
            const int wg = 2 * w + jj;
#pragma unroll
            for (int g = 0; g < 4; ++g) {
                const float gs = (g == 2) ? L2E2 : L2E;
                const int gr = g * 128 + wg * 16 + n;
#pragma unroll
                for (int kt = 0; kt < 4; ++kt) {
                    aWih1[jj][g][kt] = ldfrag_s(Wih1 + (size_t)gr * H_ + kt * 32 + q * 8, gs);
                    half8 wf = ldfrag_s(Whh1 + (size_t)gr * H_ + kt * 32 + q * 8, gs);
                    if (kt < 2) aWhh1r[jj][g][kt] = wf;
                    else        *(half8*)&whh1lds[wg][g][kt - 2][lane][0] = wf;
                }
                const int gb = g * 128 + wg * 16 + q * 4;
                f16x2 p0, p1;
                p0[0] = (f16)((bih1[gb]     + bhh1[gb])     * gs);
                p0[1] = (f16)((bih1[gb + 1] + bhh1[gb + 1]) * gs);
                p1[0] = (f16)((bih1[gb + 2] + bhh1[gb + 2]) * gs);
                p1[1] = (f16)((bih1[gb + 3] + bhh1[gb + 3]) * gs);
                b1p[jj][g][0] = p0;
                b1p[jj][g][1] = p1;
            }
        }
        floatx4 c2[2] = {{0.f, 0.f, 0.f, 0.f}, {0.f, 0.f, 0.f, 0.f}};
        __syncthreads();

        for (int p = 0; p <= T_; ++p) {
            const int cur = p & 1, nxt = cur ^ 1;
            if (p >= 1) {
                floatx4 C1[2][4];
#pragma unroll
                for (int jj = 0; jj < 2; ++jj)
#pragma unroll
                    for (int g = 0; g < 4; ++g) C1[jj][g] = floatx4{0.f, 0.f, 0.f, 0.f};
#pragma unroll
                for (int kt = 0; kt < 4; ++kt) {
                    half8 bh = *(const half8*)&h1f[cur][kt][lane][0];     // h1(p-1)
#pragma unroll
                    for (int jj = 0; jj < 2; ++jj)
#pragma unroll
                        for (int g = 0; g < 4; ++g) C1[jj][g] = MFMA(aWih1[jj][g][kt], bh, C1[jj][g]);
                }
#pragma unroll
                for (int kt = 0; kt < 2; ++kt) {
                    half8 bh = *(const half8*)&h2f[cur][kt][lane][0];     // h2(p-2), kt0-1
#pragma unroll
                    for (int jj = 0; jj < 2; ++jj)
#pragma unroll
                        for (int g = 0; g < 4; ++g) C1[jj][g] = MFMA(aWhh1r[jj][g][kt], bh, C1[jj][g]);
                }
#pragma unroll
                for (int kt = 2; kt < 4; ++kt) {
                    half8 bh = *(const half8*)&h2f[cur][kt][lane][0];     // h2(p-2), kt2-3
#pragma unroll
                    for (int jj = 0; jj < 2; ++jj) {
                        const int wg = 2 * w + jj;
#pragma unroll
                        for (int g = 0; g < 4; ++g) {
                            half8 aw = *(const half8*)&whh1lds[wg][g][kt - 2][lane][0];
                            C1[jj][g] = MFMA(aw, bh, C1[jj][g]);
                        }
                    }
                }
#pragma unroll
                for (int jj = 0; jj < 2; ++jj) {
                    half4 hp;
                    floatx4 hv;
#pragma unroll
                    for (int r = 0; r < 4; ++r) {
                        float pi = C1[jj][0][r] + (float)b1p[jj][0][r >> 1][r & 1];
                        float pf = C1[jj][1][r] + (float)b1p[jj][1][r >> 1][r & 1];
                        float pg = C1[jj][2][r] + (float)b1p[jj][2][r >> 1][r & 1];
                        float po = C1[jj][3][r] + (float)b1p[jj][3][r >> 1][r & 1];
                        float i_ = sigmP(pi), f_ = sigmP(pf), g_ = tanhP(pg), o_ = sigmP(po);
                        c2[jj][r] = f_ * c2[jj][r] + i_ * g_;
                        hv[r] = o_ * tanhC(c2[jj][r]);
                        hp[r] = (f16)hv[r];
                    }
                    const int wg = 2 * w + jj;
                    const int ktw = wg >> 1;
                    const int qw = (wg & 1) * 2 + (q >> 1);
                    const int eb = (q & 1) * 4;
                    if (n < NB) {
                        *(half4*)&h2f[nxt][ktw][n + 16 * qw][eb] = hp;
                        if (p == T_) {
#pragma unroll
                            for (int r = 0; r < 4; ++r)
                                h2last[(size_t)(b0 + n) * H_ + wg * 16 + q * 4 + r] = hv[r];
                        }
                    }
                }
            }
            __syncthreads();
        }
    }
}

// batch-norm statistics over the batch dim: 1 block, 1024 threads
__global__ void bn_stats(const float* __restrict__ h2last, float* __restrict__ stats)
{
    __shared__ float red[2][8][128];
    const int tid = threadIdx.x;
    const int j = tid & 127, bs = tid >> 7;
    float s = 0.0f, ss = 0.0f;
    for (int bb = 0; bb < 128; ++bb) {
        float v = h2last[(size_t)(bb * 8 + bs) * H_ + j];
        s += v;
        ss += v * v;
    }
    red[0][bs][j] = s;
    red[1][bs][j] = ss;
    __syncthreads();
    if (tid < 128) {
        float S = 0.0f, SS = 0.0f;
#pragma unroll
        for (int k = 0; k < 8; ++k) { S += red[0][k][tid]; SS += red[1][k][tid]; }
        float mu = S * (1.0f / 1024.0f);
        float var = SS * (1.0f / 1024.0f) - mu * mu;
        stats[tid] = mu;
        stats[128 + tid] = __builtin_amdgcn_rsqf(var + 1e-5f);
    }
}

// normalize + MLP head: 8 blocks x 128 threads, one batch element per thread
__global__ void bn_mlp(const float* __restrict__ h2last, const float* __restrict__ stats,
                       const float* __restrict__ gamma, const float* __restrict__ beta,
                       const float* __restrict__ W1, const float* __restrict__ b1,
                       const float* __restrict__ W2, const float* __restrict__ b2,
                       float* __restrict__ out)
{
    __shared__ float W1T[128][33];
    __shared__ float mus[128], isds[128], gs[128], bts[128], w2s[32];
    const int tid = threadIdx.x;
    const int b = blockIdx.x * 128 + tid;

    for (int i = tid; i < 4096; i += 128) {
        int k = i >> 7, j = i & 127;
        W1T[j][k] = W1[i];
    }
    mus[tid] = stats[tid];
    isds[tid] = stats[128 + tid];
    gs[tid] = gamma[tid];
    bts[tid] = beta[tid];
    if (tid < 32) w2s[tid] = W2[tid];
    __syncthreads();

    float z[32];
#pragma unroll
    for (int k = 0; k < 32; ++k) z[k] = b1[k];

    for (int j = 0; j < 128; ++j) {
        float nv = (h2last[(size_t)b * H_ + j] - mus[j]) * isds[j] * gs[j] + bts[j];
#pragma unroll
        for (int k = 0; k < 32; ++k) z[k] += W1T[j][k] * nv;
    }
    float o = b2[0];
#pragma unroll
    for (int k = 0; k < 32; ++k) o += w2s[k] * fmaxf(z[k], 0.0f);
    out[b] = o;
}

extern "C" void kernel_launch(void* const* d_in, const int* in_sizes, int n_in,
                              void* d_out, int out_size, void* d_ws, size_t ws_size,
                              hipStream_t stream)
{
    const float* x    = (const float*)d_in[0];
    const float* Wih0 = (const float*)d_in[1];
    const float* Whh0 = (const float*)d_in[2];
    const float* bih0 = (const float*)d_in[3];
    const float* bhh0 = (const float*)d_in[4];
    const float* Wih1 = (const float*)d_in[5];
    const float* Whh1 = (const float*)d_in[6];
    const float* bih1 = (const float*)d_in[7];
    const float* bhh1 = (const float*)d_in[8];
    const float* gamma = (const float*)d_in[9];
    const float* beta  = (const float*)d_in[10];
    const float* W1 = (const float*)d_in[11];
    const float* b1 = (const float*)d_in[12];
    const float* W2 = (const float*)d_in[13];
    const float* b2 = (const float*)d_in[14];

    float* h2last = (float*)d_ws;              // 1024*128 floats = 512 KB
    float* stats  = h2last + (size_t)B_ * H_;  // 256 floats
    float* out = (float*)d_out;

    hipLaunchKernelGGL(lstm_fused, dim3(B_ / NB), dim3(NT), 0, stream,
                       x, Wih0, Whh0, bih0, bhh0, Wih1, Whh1, bih1, bhh1, h2last);
    hipLaunchKernelGGL(bn_stats, dim3(1), dim3(1024), 0, stream, h2last, stats);
    hipLaunchKernelGGL(bn_mlp, dim3(8), dim3(128), 0, stream,
                       h2last, stats, gamma, beta, W1, b1, W2, b2, out);
}

// Round 11
// 1108.835 us; speedup vs baseline: 1.4265x; 1.3073x over previous
//
#include <hip/hip_runtime.h>

// ForexLSTM: 2-layer LSTM (B=1024, T=512, D=14, H=128) + batchnorm-over-batch + MLP(128->32->1)
//
// Round 10: R7 structure VERBATIM (best spill-free config, 1156 us) + the one change
// R9 proved good (log2e folded into gate weights -> cheaper activations), with R9's
// bad change (Whh1-kt1 register promotion -> spill) reverted.
//   - 512 thr / 8 waves; waves 0-3 layer-0 (2 j-groups each), waves 4-7 layer-1.
//   - One __syncthreads per phase, 513 phases: phase p = L0(t=p) + L1(t=p-1).
//   - Group B: Wih1 + Whh1-kt0 in regs; Whh1 kt1-3 in LDS (96 KB) -- R7's proven split.
//   - log2e fold: i/f/o gate rows x1.4427, g rows x2.8854 (also biases, Wih0-aug):
//     sigm = rcp(1+exp2(-y)), tanh = 1-2*rcp(1+exp2(y)). Saves ~6 VALU slots/state.
//   - x prefetch via incrementally-advanced pointer (no per-phase 64-bit mul chain).

#define B_ 1024
#define T_ 512
#define D_ 14
#define H_ 128
#define NB 4
#define NT 512

#define L2E 1.44269504088896f
#define L2E2 2.88539008177793f

typedef _Float16 f16;
typedef _Float16 half4 __attribute__((ext_vector_type(4)));
typedef _Float16 half8 __attribute__((ext_vector_type(8)));
typedef _Float16 f16x2 __attribute__((ext_vector_type(2)));
typedef float floatx4 __attribute__((ext_vector_type(4)));

// pre-scaled activations: y = x * L2E (sigm rows) or x * 2*L2E (tanh rows)
__device__ __forceinline__ float sigmP(float y) {
    return __builtin_amdgcn_rcpf(1.0f + __builtin_amdgcn_exp2f(-y));
}
__device__ __forceinline__ float tanhP(float y) {   // y = 2x*log2e
    return 1.0f - 2.0f * __builtin_amdgcn_rcpf(1.0f + __builtin_amdgcn_exp2f(y));
}
__device__ __forceinline__ float tanhC(float c) {   // c in true units
    return tanhP(c * L2E2);
}

__device__ __forceinline__ half8 ldfrag_s(const float* __restrict__ p, float s) {
    half8 r;
#pragma unroll
    for (int j = 0; j < 8; ++j) r[j] = (f16)(p[j] * s);
    return r;
}

#define MFMA(a, b, c) __builtin_amdgcn_mfma_f32_16x16x32_f16((a), (b), (c), 0, 0, 0)

__global__ __launch_bounds__(NT, 2) void lstm_fused(
    const float* __restrict__ x,
    const float* __restrict__ Wih0, const float* __restrict__ Whh0,
    const float* __restrict__ bih0, const float* __restrict__ bhh0,
    const float* __restrict__ Wih1, const float* __restrict__ Whh1,
    const float* __restrict__ bih1, const float* __restrict__ bhh1,
    float* __restrict__ h2last)
{
    // LDS: 96 + 8 + 8 + 2 = 114 KB
    __shared__ __align__(16) f16 whh1lds[8][4][3][64][8];  // [wg][gate][kt-1][lane][e]
    __shared__ __align__(16) f16 h1f[2][4][64][8];         // [buf][kt][lane][e] B-frag
    __shared__ __align__(16) f16 h2f[2][4][64][8];
    __shared__ __align__(16) f16 xf[2][64][8];             // x_aug (K=16: 14 x, 0, 1.0)

    const int tid = threadIdx.x;
    const int lane = tid & 63;
    const int wv = tid >> 6;          // wave 0..7
    const int n = lane & 15;          // batch column (valid < NB) / A-row index
    const int q = lane >> 4;          // quad -> D rows q*4+r
    const int b0 = blockIdx.x * NB;

    // ---- zero state buffers: h1f,h2f = 4096 dwords total; xf = 512 dwords ----
    {
        unsigned int* z1 = (unsigned int*)h1f;
        unsigned int* z2 = (unsigned int*)h2f;
#pragma unroll
        for (int i = 0; i < 4; ++i) {
            z1[tid + i * 512] = 0u;
            z2[tid + i * 512] = 0u;
        }
        ((unsigned int*)xf)[tid] = 0u;
    }
    __syncthreads();

    // ---- x_aug constants (k==15 -> 1.0 in BOTH buffers) + stage x(0) into xf[0] ----
    if (tid < NB) {
        xf[0][tid + 16][7] = (f16)1.0f;
        xf[1][tid + 16][7] = (f16)1.0f;
    }
    if (tid < 64) {
        int nn = tid & 15, kq = tid >> 4;
        if (nn < NB && kq < 2) {
            half8 v;
#pragma unroll
            for (int e = 0; e < 8; ++e) {
                int k = kq * 8 + e;
                v[e] = (k < D_) ? (f16)x[(size_t)(b0 + nn) * T_ * D_ + k]
                                : (k == 15 ? (f16)1.0f : (f16)0.0f);
            }
            *(half8*)&xf[0][tid][0] = v;
        }
    }

    // incremental x-prefetch pointer (valid only for threads < NB*D_)
    const float* xpp = x + (size_t)(b0 + (tid & 3)) * T_ * D_ + D_ + (tid >> 2);

    if (wv < 4) {
        // ================= GROUP A: layer-0, waves 0-3, j-groups {2wv, 2wv+1} ========
        half8 aWhh0[2][4][4], aWih0[2][4];
#pragma unroll
        for (int jj = 0; jj < 2; ++jj) {
            const int wg = 2 * wv + jj;
#pragma unroll
            for (int g = 0; g < 4; ++g) {
                const float gs = (g == 2) ? L2E2 : L2E;   // g-gate rows pre-scaled 2x
                const int gr = g * 128 + wg * 16 + n;
#pragma unroll
                for (int kt = 0; kt < 4; ++kt)
                    aWhh0[jj][g][kt] = ldfrag_s(Whh0 + (size_t)gr * H_ + kt * 32 + q * 8, gs);
                half8 w0;
#pragma unroll
                for (int e = 0; e < 8; ++e) {
                    int k = q * 8 + e;
                    if (k < D_)       w0[e] = (f16)(Wih0[(size_t)gr * D_ + k] * gs);
                    else if (k == 15) w0[e] = (f16)((bih0[gr] + bhh0[gr]) * gs);
                    else              w0[e] = (f16)0.0f;
                }
                aWih0[jj][g] = w0;
            }
        }
        floatx4 c1[2] = {{0.f, 0.f, 0.f, 0.f}, {0.f, 0.f, 0.f, 0.f}};
        __syncthreads();

        for (int p = 0; p <= T_; ++p) {
            const int cur = p & 1, nxt = cur ^ 1;
            if (p < T_) {
                float xp = 0.0f;
                if (tid < NB * D_ && (p + 1) < T_) xp = *xpp;

                floatx4 C0[2][4];
#pragma unroll
                for (int jj = 0; jj < 2; ++jj)
#pragma unroll
                    for (int g = 0; g < 4; ++g) C0[jj][g] = floatx4{0.f, 0.f, 0.f, 0.f};
                {
                    half8 bx = *(const half8*)&xf[cur][lane][0];
#pragma unroll
                    for (int jj = 0; jj < 2; ++jj)
#pragma unroll
                        for (int g = 0; g < 4; ++g) C0[jj][g] = MFMA(aWih0[jj][g], bx, C0[jj][g]);
                }
#pragma unroll
                for (int kt = 0; kt < 4; ++kt) {
                    half8 bh = *(const half8*)&h1f[cur][kt][lane][0];
#pragma unroll
                    for (int jj = 0; jj < 2; ++jj)
#pragma unroll
                        for (int g = 0; g < 4; ++g) C0[jj][g] = MFMA(aWhh0[jj][g][kt], bh, C0[jj][g]);
                }
#pragma unroll
                for (int jj = 0; jj < 2; ++jj) {
                    half4 hp;
#pragma unroll
                    for (int r = 0; r < 4; ++r) {
                        float i_ = sigmP(C0[jj][0][r]);
                        float f_ = sigmP(C0[jj][1][r]);
                        float g_ = tanhP(C0[jj][2][r]);
                        float o_ = sigmP(C0[jj][3][r]);
                        c1[jj][r] = f_ * c1[jj][r] + i_ * g_;
                        hp[r] = (f16)(o_ * tanhC(c1[jj][r]));
                    }
                    const int wg = 2 * wv + jj;
                    const int ktw = wg >> 1;
                    const int qw = (wg & 1) * 2 + (q >> 1);
                    const int eb = (q & 1) * 4;
                    if (n < NB) *(half4*)&h1f[nxt][ktw][n + 16 * qw][eb] = hp;
                }
                if (tid < NB * D_ && (p + 1) < T_) {
                    int k = tid >> 2;
                    xf[nxt][(tid & 3) + 16 * (k >> 3)][k & 7] = (f16)xp;
                    xpp += D_;
                }
            }
            __syncthreads();
        }
    } else {
        // ================= GROUP B: layer-1, waves 4-7, j-groups {2w, 2w+1} ==========
        const int w = wv - 4;
        half8 aWih1[2][4][4], aWhh1k0[2][4];   // Whh1 kt0 in regs; kt1-3 in LDS
        f16x2 b1p[2][4][2];
#pragma unroll
        for (int jj = 0; jj < 2; ++jj) {
            const int wg = 2 * w + jj;
#pragma unroll
            for (int g = 0; g < 4; ++g) {
                const float gs = (g == 2) ? L2E2 : L2E;
                const int gr = g * 128 + wg * 16 + n;
#pragma unroll
                for (int kt = 0; kt < 4; ++kt) {
                    aWih1[jj][g][kt] = ldfrag_s(Wih1 + (size_t)gr * H_ + kt * 32 + q * 8, gs);
                    half8 wf = ldfrag_s(Whh1 + (size_t)gr * H_ + kt * 32 + q * 8, gs);
                    if (kt == 0) aWhh1k0[jj][g] = wf;
                    else         *(half8*)&whh1lds[wg][g][kt - 1][lane][0] = wf;
                }
                const int gb = g * 128 + wg * 16 + q * 4;
                f16x2 p0, p1;
                p0[0] = (f16)((bih1[gb]     + bhh1[gb])     * gs);
                p0[1] = (f16)((bih1[gb + 1] + bhh1[gb + 1]) * gs);
                p1[0] = (f16)((bih1[gb + 2] + bhh1[gb + 2]) * gs);
                p1[1] = (f16)((bih1[gb + 3] + bhh1[gb + 3]) * gs);
                b1p[jj][g][0] = p0;
                b1p[jj][g][1] = p1;
            }
        }
        floatx4 c2[2] = {{0.f, 0.f, 0.f, 0.f}, {0.f, 0.f, 0.f, 0.f}};
        __syncthreads();

        for (int p = 0; p <= T_; ++p) {
            const int cur = p & 1, nxt = cur ^ 1;
            if (p >= 1) {
                floatx4 C1[2][4];
#pragma unroll
                for (int jj = 0; jj < 2; ++jj)
#pragma unroll
                    for (int g = 0; g < 4; ++g) C1[jj][g] = floatx4{0.f, 0.f, 0.f, 0.f};
#pragma unroll
                for (int kt = 0; kt < 4; ++kt) {
                    half8 bh = *(const half8*)&h1f[cur][kt][lane][0];     // h1(p-1)
#pragma unroll
                    for (int jj = 0; jj < 2; ++jj)
#pragma unroll
                        for (int g = 0; g < 4; ++g) C1[jj][g] = MFMA(aWih1[jj][g][kt], bh, C1[jj][g]);
                }
                {
                    half8 bh = *(const half8*)&h2f[cur][0][lane][0];      // h2(p-2), kt0
#pragma unroll
                    for (int jj = 0; jj < 2; ++jj)
#pragma unroll
                        for (int g = 0; g < 4; ++g) C1[jj][g] = MFMA(aWhh1k0[jj][g], bh, C1[jj][g]);
                }
#pragma unroll
                for (int kt = 1; kt < 4; ++kt) {
                    half8 bh = *(const half8*)&h2f[cur][kt][lane][0];     // h2(p-2), kt1-3
#pragma unroll
                    for (int jj = 0; jj < 2; ++jj) {
                        const int wg = 2 * w + jj;
#pragma unroll
                        for (int g = 0; g < 4; ++g) {
                            half8 aw = *(const half8*)&whh1lds[wg][g][kt - 1][lane][0];
                            C1[jj][g] = MFMA(aw, bh, C1[jj][g]);
                        }
                    }
                }
#pragma unroll
                for (int jj = 0; jj < 2; ++jj) {
                    half4 hp;
                    floatx4 hv;
#pragma unroll
                    for (int r = 0; r < 4; ++r) {
                        float pi = C1[jj][0][r] + (float)b1p[jj][0][r >> 1][r & 1];
                        float pf = C1[jj][1][r] + (float)b1p[jj][1][r >> 1][r & 1];
                        float pg = C1[jj][2][r] + (float)b1p[jj][2][r >> 1][r & 1];
                        float po = C1[jj][3][r] + (float)b1p[jj][3][r >> 1][r & 1];
                        float i_ = sigmP(pi), f_ = sigmP(pf), g_ = tanhP(pg), o_ = sigmP(po);
                        c2[jj][r] = f_ * c2[jj][r] + i_ * g_;
                        hv[r] = o_ * tanhC(c2[jj][r]);
                        hp[r] = (f16)hv[r];
                    }
                    const int wg = 2 * w + jj;
                    const int ktw = wg >> 1;
                    const int qw = (wg & 1) * 2 + (q >> 1);
                    const int eb = (q & 1) * 4;
                    if (n < NB) {
                        *(half4*)&h2f[nxt][ktw][n + 16 * qw][eb] = hp;
                        if (p == T_) {
#pragma unroll
                            for (int r = 0; r < 4; ++r)
                                h2last[(size_t)(b0 + n) * H_ + wg * 16 + q * 4 + r] = hv[r];
                        }
                    }
                }
            }
            __syncthreads();
        }
    }
}

// batch-norm statistics over the batch dim: 1 block, 1024 threads
__global__ void bn_stats(const float* __restrict__ h2last, float* __restrict__ stats)
{
    __shared__ float red[2][8][128];
    const int tid = threadIdx.x;
    const int j = tid & 127, bs = tid >> 7;
    float s = 0.0f, ss = 0.0f;
    for (int bb = 0; bb < 128; ++bb) {
        float v = h2last[(size_t)(bb * 8 + bs) * H_ + j];
        s += v;
        ss += v * v;
    }
    red[0][bs][j] = s;
    red[1][bs][j] = ss;
    __syncthreads();
    if (tid < 128) {
        float S = 0.0f, SS = 0.0f;
#pragma unroll
        for (int k = 0; k < 8; ++k) { S += red[0][k][tid]; SS += red[1][k][tid]; }
        float mu = S * (1.0f / 1024.0f);
        float var = SS * (1.0f / 1024.0f) - mu * mu;
        stats[tid] = mu;
        stats[128 + tid] = __builtin_amdgcn_rsqf(var + 1e-5f);
    }
}

// normalize + MLP head: 8 blocks x 128 threads, one batch element per thread
__global__ void bn_mlp(const float* __restrict__ h2last, const float* __restrict__ stats,
                       const float* __restrict__ gamma, const float* __restrict__ beta,
                       const float* __restrict__ W1, const float* __restrict__ b1,
                       const float* __restrict__ W2, const float* __restrict__ b2,
                       float* __restrict__ out)
{
    __shared__ float W1T[128][33];
    __shared__ float mus[128], isds[128], gs[128], bts[128], w2s[32];
    const int tid = threadIdx.x;
    const int b = blockIdx.x * 128 + tid;

    for (int i = tid; i < 4096; i += 128) {
        int k = i >> 7, j = i & 127;
        W1T[j][k] = W1[i];
    }
    mus[tid] = stats[tid];
    isds[tid] = stats[128 + tid];
    gs[tid] = gamma[tid];
    bts[tid] = beta[tid];
    if (tid < 32) w2s[tid] = W2[tid];
    __syncthreads();

    float z[32];
#pragma unroll
    for (int k = 0; k < 32; ++k) z[k] = b1[k];

    for (int j = 0; j < 128; ++j) {
        float nv = (h2last[(size_t)b * H_ + j] - mus[j]) * isds[j] * gs[j] + bts[j];
#pragma unroll
        for (int k = 0; k < 32; ++k) z[k] += W1T[j][k] * nv;
    }
    float o = b2[0];
#pragma unroll
    for (int k = 0; k < 32; ++k) o += w2s[k] * fmaxf(z[k], 0.0f);
    out[b] = o;
}

extern "C" void kernel_launch(void* const* d_in, const int* in_sizes, int n_in,
                              void* d_out, int out_size, void* d_ws, size_t ws_size,
                              hipStream_t stream)
{
    const float* x    = (const float*)d_in[0];
    const float* Wih0 = (const float*)d_in[1];
    const float* Whh0 = (const float*)d_in[2];
    const float* bih0 = (const float*)d_in[3];
    const float* bhh0 = (const float*)d_in[4];
    const float* Wih1 = (const float*)d_in[5];
    const float* Whh1 = (const float*)d_in[6];
    const float* bih1 = (const float*)d_in[7];
    const float* bhh1 = (const float*)d_in[8];
    const float* gamma = (const float*)d_in[9];
    const float* beta  = (const float*)d_in[10];
    const float* W1 = (const float*)d_in[11];
    const float* b1 = (const float*)d_in[12];
    const float* W2 = (const float*)d_in[13];
    const float* b2 = (const float*)d_in[14];

    float* h2last = (float*)d_ws;              // 1024*128 floats = 512 KB
    float* stats  = h2last + (size_t)B_ * H_;  // 256 floats
    float* out = (float*)d_out;

    hipLaunchKernelGGL(lstm_fused, dim3(B_ / NB), dim3(NT), 0, stream,
                       x, Wih0, Whh0, bih0, bhh0, Wih1, Whh1, bih1, bhh1, h2last);
    hipLaunchKernelGGL(bn_stats, dim3(1), dim3(1024), 0, stream, h2last, stats);
    hipLaunchKernelGGL(bn_mlp, dim3(8), dim3(128), 0, stream,
                       h2last, stats, gamma, beta, W1, b1, W2, b2, out);
}